// Round 14
// baseline (54.954 us; speedup 1.0000x reference)
//
#include <hip/hip_runtime.h>
#include <hip/hip_bf16.h>

#define IN_C 192
#define HW   9600   // 80*120
#define NPIX 128    // pixels per block (8 waves x 16-px strips)

typedef __attribute__((ext_vector_type(8))) short bf16x8;
typedef __attribute__((ext_vector_type(4))) float f32x4;

static __device__ __forceinline__ short f2bf(float f) {
  return __builtin_bit_cast(short, __float2bfloat16(f));   // RNE
}

// Single-kernel version of the best-measured structure (R6/R9, 49.0us):
// the separate pack_w launch (~3-5us serial head on every replay) is folded
// into the prologue - each block packs W fp32 -> bf16 fragments directly
// into its LDS (validated in R7/R8: same code, no spill, VGPR 64).
// Invariants (R5/R6 validated, kept byte-identical):
//  - W af reads come from LDS (lgkmcnt stream): the K-loop's ONLY vmcnt ops
//    are x prefetches -> the depth-3 rotation stays in flight.
//  - x read exactly once from HBM; no barriers after the prologue;
//    bias loads are epilogue-only (post-MFMA).
//  - straight-line unrolled K-steps (R7 scratch-spill lesson).
// Fragment convention: lane l of frag (fo,kk): o = fo*16+(l&15),
// k = kk*32+(l>>4)*8+j - same k(l,j) as the x B-frags, so any true
// intra-fragment k-permutation cancels (validated R1).
__global__ __launch_bounds__(512, 4) void conv_mfma_kernel(
    const float* __restrict__ x, const float* __restrict__ W,
    const float* __restrict__ bias, float* __restrict__ out) {
  __shared__ short wl[12 * 6 * 64 * 8];   // 73728 B packed-fragment W

  const int tid  = threadIdx.x;
  const int wid  = tid >> 6;
  const int lane = tid & 63;
  const int c    = lane & 15;
  const int g    = lane >> 4;
  const int b    = blockIdx.y;
  const int p    = blockIdx.x * NPIX + wid * 16 + c;   // this lane's pixel

  // lane's x column base: k = kk*32 + g*8 + j  ->  xp[(kk*32 + j)*HW]
  const float* xp = x + (size_t)b * IN_C * HW + (size_t)(g * 8) * HW + p;

  float xA[8], xB[8], xC[8], xD[8];

#define LOADX(DST, KK)                                                \
  { _Pragma("unroll")                                                 \
    for (int j = 0; j < 8; ++j)                                       \
      DST[j] = xp[(size_t)((KK) * 32 + j) * HW]; }

  // ---- Prologue: x k0..k2 first (HBM latency hides under the W pack),
  // then pack W fp32 -> bf16 fragments straight into LDS (L2-hot source).
  LOADX(xA, 0);
  LOADX(xB, 1);
  LOADX(xC, 2);
#pragma unroll
  for (int i = 0; i < 9; ++i) {
    const int chunk = i * 512 + tid;     // 0..4607
    const int fo  = chunk / (6 * 64);
    const int rem = chunk % (6 * 64);
    const int kk  = rem / 64;
    const int l   = rem & 63;
    const int o   = fo * 16 + (l & 15);
    const int kb  = kk * 32 + (l >> 4) * 8;
    bf16x8 v;
#pragma unroll
    for (int j = 0; j < 8; ++j) v[j] = f2bf(W[o * IN_C + kb + j]);
    *reinterpret_cast<bf16x8*>(wl + (size_t)chunk * 8) = v;
  }
  __syncthreads();   // W staged; everything below is barrier-free

  f32x4 acc[12];
#pragma unroll
  for (int m = 0; m < 12; ++m) acc[m] = (f32x4)0.0f;

  // af from LDS in batches of 3 (12 transient VGPRs) to bound pressure.
#define KSTEP(CURB, PFB, PFKK, PFEN, KK)                              \
  {                                                                   \
    if (PFEN) { LOADX(PFB, PFKK); }                                   \
    bf16x8 bfr;                                                       \
    _Pragma("unroll")                                                 \
    for (int j = 0; j < 8; ++j) bfr[j] = f2bf(CURB[j]);               \
    _Pragma("unroll")                                                 \
    for (int h = 0; h < 4; ++h) {                                     \
      bf16x8 af[3];                                                   \
      _Pragma("unroll")                                               \
      for (int m = 0; m < 3; ++m)                                     \
        af[m] = *reinterpret_cast<const bf16x8*>(                     \
            wl + (size_t)((((h * 3 + m) * 6 + (KK)) * 64) + lane) * 8); \
      _Pragma("unroll")                                               \
      for (int m = 0; m < 3; ++m)                                     \
        acc[h * 3 + m] = __builtin_amdgcn_mfma_f32_16x16x32_bf16(     \
            af[m], bfr, acc[h * 3 + m], 0, 0, 0);                     \
    }                                                                 \
  }

  KSTEP(xA, xD, 3, true,  0);   // consume k0, prefetch k3 (3-step lead)
  KSTEP(xB, xA, 4, true,  1);   // consume k1, prefetch k4
  KSTEP(xC, xB, 5, true,  2);   // consume k2, prefetch k5
  KSTEP(xD, xA, 0, false, 3);   // consume k3
  KSTEP(xA, xB, 0, false, 4);   // consume k4
  KSTEP(xB, xC, 0, false, 5);   // consume k5
#undef KSTEP
#undef LOADX

  // Epilogue: C/D col = lane&15 (pixel, == c), row = g*4 + r (out-ch).
  const int hi = p / 120;
  const int wi = p - hi * 120;
#pragma unroll
  for (int mo = 0; mo < 12; ++mo) {
    const int ob = mo * 16 + g * 4;
    const f32x4 bv = *reinterpret_cast<const f32x4*>(bias + ob);
    const f32x4 v  = acc[mo];
#pragma unroll
    for (int r = 0; r < 4; ++r) {
      const int o  = ob + r;
      const int co = o >> 6;
      const int br = (o >> 3) & 7;
      const int bc = o & 7;
      const int idx = ((b * 3 + co) * 640 + br * 80 + hi) * 960 + bc * 120 + wi;
      out[idx] = v[r] + bv[r];
    }
  }
}

extern "C" void kernel_launch(void* const* d_in, const int* in_sizes, int n_in,
                              void* d_out, int out_size, void* d_ws, size_t ws_size,
                              hipStream_t stream) {
  const float* x    = (const float*)d_in[0];
  const float* W    = (const float*)d_in[1];
  const float* bias = (const float*)d_in[2];
  float* out = (float*)d_out;

  dim3 grid(75, 16);  // 75 pixel tiles of 128 (9600 exact), 16 batches
  conv_mfma_kernel<<<grid, 512, 0, stream>>>(x, W, bias, out);
}